// Round 5
// baseline (159.228 us; speedup 1.0000x reference)
//
#include <hip/hip_runtime.h>

#define B_ 8
#define N_ 1024
#define DIM_ 512
#define H_ 8
#define D_ 64
#define PD_ 50

typedef __attribute__((ext_vector_type(4))) float f32x4;
typedef __attribute__((ext_vector_type(8))) __bf16 bf16x8;

__device__ __forceinline__ unsigned short f2bf(float f) {
    unsigned int u = __float_as_uint(f);
    u += 0x7FFFu + ((u >> 16) & 1u);   // round-to-nearest-even
    return (unsigned short)(u >> 16);
}

// ---------------- fp32 -> bf16 cast (vectorized x4) ----------------
__global__ __launch_bounds__(256) void cast_f32_bf16(const float* __restrict__ in,
                                                     unsigned short* __restrict__ out, int n4) {
    int i = blockIdx.x * blockDim.x + threadIdx.x;
    if (i >= n4) return;
    float4 v = reinterpret_cast<const float4*>(in)[i];
    ushort4 o;
    o.x = f2bf(v.x); o.y = f2bf(v.y); o.z = f2bf(v.z); o.w = f2bf(v.w);
    reinterpret_cast<ushort4*>(out)[i] = o;
}

// ---------------- pos_bias[i][j] = sum_p pos[i][j][p] * w_pos[p] ----------------
__global__ __launch_bounds__(256) void pos_bias_kernel(const float* __restrict__ pos,
                                                       const float* __restrict__ w_pos,
                                                       float* __restrict__ pb) {
    int idx = blockIdx.x * blockDim.x + threadIdx.x;   // one (i,j) pair
    const float* p = pos + (size_t)idx * PD_;
    float acc = 0.f;
#pragma unroll
    for (int t = 0; t < PD_ / 2; t++) {
        float2 v = reinterpret_cast<const float2*>(p)[t];
        float2 w = reinterpret_cast<const float2*>(w_pos)[t];
        acc += v.x * w.x + v.y * w.y;
    }
    pb[idx] = acc;
}

// ---------------- kv = x @ W_kv^T, scatter to kb[b][h][n][d] and vt[b][h][d][n] ----------------
__global__ __launch_bounds__(256) void kv_gemm(const unsigned short* __restrict__ xb,
                                               const unsigned short* __restrict__ wb,
                                               unsigned short* __restrict__ kb,
                                               unsigned short* __restrict__ vt) {
    __shared__ __align__(16) unsigned short As[64][40];   // +8 pad
    __shared__ __align__(16) unsigned short Bs[64][40];
    const int m0 = blockIdx.x * 64;
    const int n0 = blockIdx.y * 64;
    const int t = threadIdx.x;
    const int w = t >> 6, l = t & 63;
    const int wr = (w >> 1) * 32, wc = (w & 1) * 32;
    const int lr = l & 15, lg = l >> 4;
    const int sr = t >> 2, sk = (t & 3) * 8;

    f32x4 acc[2][2] = {};

    for (int k0 = 0; k0 < DIM_; k0 += 32) {
        __syncthreads();
        *reinterpret_cast<bf16x8*>(&As[sr][sk]) =
            *reinterpret_cast<const bf16x8*>(&xb[(size_t)(m0 + sr) * DIM_ + k0 + sk]);
        *reinterpret_cast<bf16x8*>(&Bs[sr][sk]) =
            *reinterpret_cast<const bf16x8*>(&wb[(size_t)(n0 + sr) * DIM_ + k0 + sk]);
        __syncthreads();
        bf16x8 a0 = *reinterpret_cast<const bf16x8*>(&As[wr + lr][lg * 8]);
        bf16x8 a1 = *reinterpret_cast<const bf16x8*>(&As[wr + 16 + lr][lg * 8]);
        bf16x8 b0 = *reinterpret_cast<const bf16x8*>(&Bs[wc + lr][lg * 8]);
        bf16x8 b1 = *reinterpret_cast<const bf16x8*>(&Bs[wc + 16 + lr][lg * 8]);
        acc[0][0] = __builtin_amdgcn_mfma_f32_16x16x32_bf16(a0, b0, acc[0][0], 0, 0, 0);
        acc[0][1] = __builtin_amdgcn_mfma_f32_16x16x32_bf16(a0, b1, acc[0][1], 0, 0, 0);
        acc[1][0] = __builtin_amdgcn_mfma_f32_16x16x32_bf16(a1, b0, acc[1][0], 0, 0, 0);
        acc[1][1] = __builtin_amdgcn_mfma_f32_16x16x32_bf16(a1, b1, acc[1][1], 0, 0, 0);
    }

#pragma unroll
    for (int fm = 0; fm < 2; fm++)
#pragma unroll
        for (int fn = 0; fn < 2; fn++) {
            int gn = n0 + wc + fn * 16 + lr;
#pragma unroll
            for (int i = 0; i < 4; i++) {
                int gm = m0 + wr + fm * 16 + lg * 4 + i;
                unsigned short bv = f2bf(acc[fm][fn][i]);
                int b = gm >> 10, nseq = gm & 1023;
                if (gn < DIM_) {
                    int h = gn >> 6, d = gn & 63;
                    kb[(((size_t)(b * H_ + h) * N_) + nseq) * D_ + d] = bv;
                } else {
                    int c = gn - DIM_;
                    int h = c >> 6, d = c & 63;
                    vt[(((size_t)(b * H_ + h) * D_) + d) * N_ + nseq] = bv;
                }
            }
        }
}

// ---------------- flash attention: S = (k k^T)*alpha + pb, softmax, O = P v ----------------
__global__ __launch_bounds__(256) void attn_kernel(const unsigned short* __restrict__ kb,
                                                   const unsigned short* __restrict__ vt,
                                                   const float* __restrict__ pb,
                                                   const float* __restrict__ w_pos,
                                                   unsigned short* __restrict__ oh) {
    const int qt = blockIdx.x;   // 0..15
    const int bh = blockIdx.y;   // 0..63  (b*8 + h)
    const int b = bh >> 3, h = bh & 7;
    __shared__ __align__(16) unsigned short Qs[64][72];
    __shared__ __align__(16) unsigned short Ks[64][72];
    __shared__ __align__(16) unsigned short Vs[64][72];     // Vs[d][j_local]
    __shared__ __align__(16) unsigned short Ps[4][16][72];  // per-wave P tile
    const int t = threadIdx.x, w = t >> 6, l = t & 63, lr = l & 15, lg = l >> 4;

    float sw = 0.f;
    for (int p = 0; p < PD_; p++) sw += w_pos[p];
    const float alpha = sw * 0.044194173824159216f;  // 512^-0.5 * sum(w_pos); b_pos dropped (softmax shift-invariant)

    const unsigned short* kh = kb + (size_t)bh * N_ * D_;
    const unsigned short* vh = vt + (size_t)bh * D_ * N_;
    const int q0 = qt * 64;
    const int sr = t >> 2, sk = (t & 3) * 8;

    // stage Q tile (64 x 64): two 8-elem halves per thread
    *reinterpret_cast<bf16x8*>(&Qs[sr][sk]) =
        *reinterpret_cast<const bf16x8*>(&kh[(size_t)(q0 + sr) * D_ + sk]);
    *reinterpret_cast<bf16x8*>(&Qs[sr][sk + 32]) =
        *reinterpret_cast<const bf16x8*>(&kh[(size_t)(q0 + sr) * D_ + sk + 32]);

    float m_run[4], l_run[4];
    f32x4 acc[4] = {};
#pragma unroll
    for (int i = 0; i < 4; i++) { m_run[i] = -1e30f; l_run[i] = 0.f; }

    for (int jt = 0; jt < 16; jt++) {
        const int j0 = jt * 64;
        __syncthreads();
        *reinterpret_cast<bf16x8*>(&Ks[sr][sk]) =
            *reinterpret_cast<const bf16x8*>(&kh[(size_t)(j0 + sr) * D_ + sk]);
        *reinterpret_cast<bf16x8*>(&Ks[sr][sk + 32]) =
            *reinterpret_cast<const bf16x8*>(&kh[(size_t)(j0 + sr) * D_ + sk + 32]);
        *reinterpret_cast<bf16x8*>(&Vs[sr][sk]) =
            *reinterpret_cast<const bf16x8*>(&vh[(size_t)sr * N_ + j0 + sk]);
        *reinterpret_cast<bf16x8*>(&Vs[sr][sk + 32]) =
            *reinterpret_cast<const bf16x8*>(&vh[(size_t)sr * N_ + j0 + sk + 32]);
        __syncthreads();

        // S = Q K^T  (16 rows x 64 cols per wave)
        f32x4 s[4] = {};
        bf16x8 aq0 = *reinterpret_cast<const bf16x8*>(&Qs[w * 16 + lr][lg * 8]);
        bf16x8 aq1 = *reinterpret_cast<const bf16x8*>(&Qs[w * 16 + lr][32 + lg * 8]);
#pragma unroll
        for (int fn = 0; fn < 4; fn++) {
            bf16x8 bk0 = *reinterpret_cast<const bf16x8*>(&Ks[fn * 16 + lr][lg * 8]);
            bf16x8 bk1 = *reinterpret_cast<const bf16x8*>(&Ks[fn * 16 + lr][32 + lg * 8]);
            s[fn] = __builtin_amdgcn_mfma_f32_16x16x32_bf16(aq0, bk0, s[fn], 0, 0, 0);
            s[fn] = __builtin_amdgcn_mfma_f32_16x16x32_bf16(aq1, bk1, s[fn], 0, 0, 0);
        }

        float sc[4][4], rowmax[4];
#pragma unroll
        for (int i = 0; i < 4; i++) rowmax[i] = -1e30f;
#pragma unroll
        for (int fn = 0; fn < 4; fn++) {
            int gj = j0 + fn * 16 + lr;
#pragma unroll
            for (int i = 0; i < 4; i++) {
                int gq = q0 + w * 16 + lg * 4 + i;
                float v = s[fn][i] * alpha + pb[(size_t)gq * N_ + gj];
                sc[fn][i] = v;
                rowmax[i] = fmaxf(rowmax[i], v);
            }
        }
#pragma unroll
        for (int msk = 1; msk < 16; msk <<= 1)
#pragma unroll
            for (int i = 0; i < 4; i++) rowmax[i] = fmaxf(rowmax[i], __shfl_xor(rowmax[i], msk));

        float mnew[4], scl[4], rs[4];
#pragma unroll
        for (int i = 0; i < 4; i++) {
            mnew[i] = fmaxf(m_run[i], rowmax[i]);
            scl[i] = __expf(m_run[i] - mnew[i]);
            rs[i] = 0.f;
        }
#pragma unroll
        for (int fn = 0; fn < 4; fn++)
#pragma unroll
            for (int i = 0; i < 4; i++) {
                float p = __expf(sc[fn][i] - mnew[i]);
                sc[fn][i] = p;
                rs[i] += p;
            }
#pragma unroll
        for (int msk = 1; msk < 16; msk <<= 1)
#pragma unroll
            for (int i = 0; i < 4; i++) rs[i] += __shfl_xor(rs[i], msk);
#pragma unroll
        for (int i = 0; i < 4; i++) {
            l_run[i] = l_run[i] * scl[i] + rs[i];
            m_run[i] = mnew[i];
        }
#pragma unroll
        for (int fd = 0; fd < 4; fd++)
#pragma unroll
            for (int i = 0; i < 4; i++) acc[fd][i] *= scl[i];

        // P -> LDS, then barrier (orders scalar P-stores before vector P-loads)
#pragma unroll
        for (int fn = 0; fn < 4; fn++)
#pragma unroll
            for (int i = 0; i < 4; i++)
                Ps[w][lg * 4 + i][fn * 16 + lr] = f2bf(sc[fn][i]);

        __syncthreads();

        bf16x8 pa0 = *reinterpret_cast<const bf16x8*>(&Ps[w][lr][lg * 8]);
        bf16x8 pa1 = *reinterpret_cast<const bf16x8*>(&Ps[w][lr][32 + lg * 8]);
#pragma unroll
        for (int fd = 0; fd < 4; fd++) {
            bf16x8 bv0 = *reinterpret_cast<const bf16x8*>(&Vs[fd * 16 + lr][lg * 8]);
            bf16x8 bv1 = *reinterpret_cast<const bf16x8*>(&Vs[fd * 16 + lr][32 + lg * 8]);
            acc[fd] = __builtin_amdgcn_mfma_f32_16x16x32_bf16(pa0, bv0, acc[fd], 0, 0, 0);
            acc[fd] = __builtin_amdgcn_mfma_f32_16x16x32_bf16(pa1, bv1, acc[fd], 0, 0, 0);
        }
    }

#pragma unroll
    for (int fd = 0; fd < 4; fd++) {
        int dcol = h * 64 + fd * 16 + lr;
#pragma unroll
        for (int i = 0; i < 4; i++) {
            int gq = q0 + w * 16 + lg * 4 + i;
            oh[((size_t)(b * N_ + gq)) * DIM_ + dcol] = f2bf(acc[fd][i] / l_run[i]);
        }
    }
}

// ---------------- final = oh @ W_out^T + b_out -> FLOAT32 d_out ----------------
__global__ __launch_bounds__(256) void out_gemm(const unsigned short* __restrict__ ohb,
                                                const unsigned short* __restrict__ wob,
                                                const float* __restrict__ b_out,
                                                float* __restrict__ out) {
    __shared__ __align__(16) unsigned short As[64][40];
    __shared__ __align__(16) unsigned short Bs[64][40];
    const int m0 = blockIdx.x * 64;
    const int n0 = blockIdx.y * 64;
    const int t = threadIdx.x;
    const int w = t >> 6, l = t & 63;
    const int wr = (w >> 1) * 32, wc = (w & 1) * 32;
    const int lr = l & 15, lg = l >> 4;
    const int sr = t >> 2, sk = (t & 3) * 8;

    f32x4 acc[2][2] = {};

    for (int k0 = 0; k0 < DIM_; k0 += 32) {
        __syncthreads();
        *reinterpret_cast<bf16x8*>(&As[sr][sk]) =
            *reinterpret_cast<const bf16x8*>(&ohb[(size_t)(m0 + sr) * DIM_ + k0 + sk]);
        *reinterpret_cast<bf16x8*>(&Bs[sr][sk]) =
            *reinterpret_cast<const bf16x8*>(&wob[(size_t)(n0 + sr) * DIM_ + k0 + sk]);
        __syncthreads();
        bf16x8 a0 = *reinterpret_cast<const bf16x8*>(&As[wr + lr][lg * 8]);
        bf16x8 a1 = *reinterpret_cast<const bf16x8*>(&As[wr + 16 + lr][lg * 8]);
        bf16x8 b0 = *reinterpret_cast<const bf16x8*>(&Bs[wc + lr][lg * 8]);
        bf16x8 b1 = *reinterpret_cast<const bf16x8*>(&Bs[wc + 16 + lr][lg * 8]);
        acc[0][0] = __builtin_amdgcn_mfma_f32_16x16x32_bf16(a0, b0, acc[0][0], 0, 0, 0);
        acc[0][1] = __builtin_amdgcn_mfma_f32_16x16x32_bf16(a0, b1, acc[0][1], 0, 0, 0);
        acc[1][0] = __builtin_amdgcn_mfma_f32_16x16x32_bf16(a1, b0, acc[1][0], 0, 0, 0);
        acc[1][1] = __builtin_amdgcn_mfma_f32_16x16x32_bf16(a1, b1, acc[1][1], 0, 0, 0);
    }

#pragma unroll
    for (int fm = 0; fm < 2; fm++)
#pragma unroll
        for (int fn = 0; fn < 2; fn++) {
            int gn = n0 + wc + fn * 16 + lr;
            float bias = b_out[gn];
#pragma unroll
            for (int i = 0; i < 4; i++) {
                int gm = m0 + wr + fm * 16 + lg * 4 + i;
                out[(size_t)gm * DIM_ + gn] = acc[fm][fn][i] + bias;
            }
        }
}

extern "C" void kernel_launch(void* const* d_in, const int* in_sizes, int n_in,
                              void* d_out, int out_size, void* d_ws, size_t ws_size,
                              hipStream_t stream) {
    const float* x     = (const float*)d_in[0];
    const float* pos   = (const float*)d_in[1];
    const float* W_kv  = (const float*)d_in[2];
    const float* W_out = (const float*)d_in[3];
    const float* b_out = (const float*)d_in[4];
    const float* w_pos = (const float*)d_in[5];
    // d_in[6] = b_pos: scalar added to every score -> softmax-invariant -> unused.

    char* ws = (char*)d_ws;
    unsigned short* xb   = (unsigned short*)(ws);               // 8 MB   x in bf16
    unsigned short* wkv  = (unsigned short*)(ws + 8388608);     // 1 MB   W_kv bf16
    unsigned short* wout = (unsigned short*)(ws + 9437184);     // 0.5 MB W_out bf16
    unsigned short* kb   = (unsigned short*)(ws + 9961472);     // 8 MB   k[b][h][n][d]
    unsigned short* vt   = (unsigned short*)(ws + 18350080);    // 8 MB   v^T[b][h][d][n]
    float*          pb   = (float*)(ws + 26738688);             // 4 MB   pos_bias fp32
    unsigned short* oh   = (unsigned short*)(ws + 30932992);    // 8 MB   attn out (b,n,h*d)
    float*          out  = (float*)d_out;                       // FLOAT32 output

    cast_f32_bf16<<<4096, 256, 0, stream>>>(x, xb, (B_ * N_ * DIM_) / 4);
    cast_f32_bf16<<<512, 256, 0, stream>>>(W_kv, wkv, (2 * DIM_ * DIM_) / 4);
    cast_f32_bf16<<<256, 256, 0, stream>>>(W_out, wout, (DIM_ * DIM_) / 4);
    pos_bias_kernel<<<4096, 256, 0, stream>>>(pos, w_pos, pb);
    kv_gemm<<<dim3(128, 16), 256, 0, stream>>>(xb, wkv, kb, vt);
    attn_kernel<<<dim3(16, 64), 256, 0, stream>>>(kb, vt, pb, w_pos, oh);
    out_gemm<<<dim3(128, 8), 256, 0, stream>>>(oh, wout, b_out, out);
}

// Round 6
// 154.585 us; speedup vs baseline: 1.0300x; 1.0300x over previous
//
#include <hip/hip_runtime.h>

#define B_ 8
#define N_ 1024
#define DIM_ 512
#define H_ 8
#define D_ 64
#define PD_ 50
#define PBROWS 256

typedef __attribute__((ext_vector_type(4))) float f32x4;
typedef __attribute__((ext_vector_type(8))) __bf16 bf16x8;

__device__ __forceinline__ unsigned short f2bf(float f) {
    unsigned int u = __float_as_uint(f);
    u += 0x7FFFu + ((u >> 16) & 1u);   // round-to-nearest-even
    return (unsigned short)(u >> 16);
}

// ---------------- fp32 -> bf16 cast (vectorized x4) ----------------
__global__ __launch_bounds__(256) void cast_f32_bf16(const float* __restrict__ in,
                                                     unsigned short* __restrict__ out, int n4) {
    int i = blockIdx.x * blockDim.x + threadIdx.x;
    if (i >= n4) return;
    float4 v = reinterpret_cast<const float4*>(in)[i];
    ushort4 o;
    o.x = f2bf(v.x); o.y = f2bf(v.y); o.z = f2bf(v.z); o.w = f2bf(v.w);
    reinterpret_cast<ushort4*>(out)[i] = o;
}

// ---------------- pos_bias: LDS-staged, coalesced float4 global loads ----------------
__global__ __launch_bounds__(256) void pos_bias_kernel(const float* __restrict__ pos,
                                                       const float* __restrict__ w_pos,
                                                       float* __restrict__ pb) {
    __shared__ float buf[PBROWS * PD_];   // 51.2 KB
    const int t = threadIdx.x;
    const size_t base = (size_t)blockIdx.x * (PBROWS * PD_);
    const float4* src = reinterpret_cast<const float4*>(pos + base);
    float4* dst = reinterpret_cast<float4*>(buf);
#pragma unroll 4
    for (int i = t; i < PBROWS * PD_ / 4; i += 256)
        dst[i] = src[i];
    __syncthreads();
    float acc = 0.f;
    const float* row = buf + t * PD_;
#pragma unroll
    for (int p = 0; p < PD_; p++) acc += row[p] * w_pos[p];
    pb[(size_t)blockIdx.x * PBROWS + t] = acc;
}

// ---------------- kv = x @ W_kv^T, scatter to kb[b][h][n][d] and vt[b][h][d][n] ----------------
__global__ __launch_bounds__(256) void kv_gemm(const unsigned short* __restrict__ xb,
                                               const unsigned short* __restrict__ wb,
                                               unsigned short* __restrict__ kb,
                                               unsigned short* __restrict__ vt) {
    __shared__ __align__(16) unsigned short As[64][40];   // +8 pad
    __shared__ __align__(16) unsigned short Bs[64][40];
    const int m0 = blockIdx.x * 64;
    const int n0 = blockIdx.y * 64;
    const int t = threadIdx.x;
    const int w = t >> 6, l = t & 63;
    const int wr = (w >> 1) * 32, wc = (w & 1) * 32;
    const int lr = l & 15, lg = l >> 4;
    const int sr = t >> 2, sk = (t & 3) * 8;

    f32x4 acc[2][2] = {};

    for (int k0 = 0; k0 < DIM_; k0 += 32) {
        __syncthreads();
        *reinterpret_cast<bf16x8*>(&As[sr][sk]) =
            *reinterpret_cast<const bf16x8*>(&xb[(size_t)(m0 + sr) * DIM_ + k0 + sk]);
        *reinterpret_cast<bf16x8*>(&Bs[sr][sk]) =
            *reinterpret_cast<const bf16x8*>(&wb[(size_t)(n0 + sr) * DIM_ + k0 + sk]);
        __syncthreads();
        bf16x8 a0 = *reinterpret_cast<const bf16x8*>(&As[wr + lr][lg * 8]);
        bf16x8 a1 = *reinterpret_cast<const bf16x8*>(&As[wr + 16 + lr][lg * 8]);
        bf16x8 b0 = *reinterpret_cast<const bf16x8*>(&Bs[wc + lr][lg * 8]);
        bf16x8 b1 = *reinterpret_cast<const bf16x8*>(&Bs[wc + 16 + lr][lg * 8]);
        acc[0][0] = __builtin_amdgcn_mfma_f32_16x16x32_bf16(a0, b0, acc[0][0], 0, 0, 0);
        acc[0][1] = __builtin_amdgcn_mfma_f32_16x16x32_bf16(a0, b1, acc[0][1], 0, 0, 0);
        acc[1][0] = __builtin_amdgcn_mfma_f32_16x16x32_bf16(a1, b0, acc[1][0], 0, 0, 0);
        acc[1][1] = __builtin_amdgcn_mfma_f32_16x16x32_bf16(a1, b1, acc[1][1], 0, 0, 0);
    }

#pragma unroll
    for (int fm = 0; fm < 2; fm++)
#pragma unroll
        for (int fn = 0; fn < 2; fn++) {
            int gn = n0 + wc + fn * 16 + lr;
#pragma unroll
            for (int i = 0; i < 4; i++) {
                int gm = m0 + wr + fm * 16 + lg * 4 + i;
                unsigned short bv = f2bf(acc[fm][fn][i]);
                int b = gm >> 10, nseq = gm & 1023;
                if (gn < DIM_) {
                    int h = gn >> 6, d = gn & 63;
                    kb[(((size_t)(b * H_ + h) * N_) + nseq) * D_ + d] = bv;
                } else {
                    int c = gn - DIM_;
                    int h = c >> 6, d = c & 63;
                    vt[(((size_t)(b * H_ + h) * D_) + d) * N_ + nseq] = bv;
                }
            }
        }
}

// ---------------- flash attention: S = (k k^T)*alpha + pb, softmax, O = P v ----------------
// grid: x = bh (fast axis -> co-resident blocks share one pb slice), y = qt
__global__ __launch_bounds__(256) void attn_kernel(const unsigned short* __restrict__ kb,
                                                   const unsigned short* __restrict__ vt,
                                                   const float* __restrict__ pb,
                                                   const float* __restrict__ w_pos,
                                                   unsigned short* __restrict__ oh) {
    const int bh = blockIdx.x;   // 0..63  (b*8 + h)
    const int qt = blockIdx.y;   // 0..15
    const int b = bh >> 3, h = bh & 7;
    __shared__ __align__(16) unsigned short Qs[64][72];
    __shared__ __align__(16) unsigned short Ks[64][72];
    __shared__ __align__(16) unsigned short Vs[64][72];     // Vs[d][j_local]
    __shared__ __align__(16) unsigned short Ps[4][16][72];  // per-wave P tile
    const int t = threadIdx.x, w = t >> 6, l = t & 63, lr = l & 15, lg = l >> 4;

    float sw = 0.f;
    for (int p = 0; p < PD_; p++) sw += w_pos[p];
    const float alpha = sw * 0.044194173824159216f;  // 512^-0.5 * sum(w_pos); b_pos dropped (softmax shift-invariant)

    const unsigned short* kh = kb + (size_t)bh * N_ * D_;
    const unsigned short* vh = vt + (size_t)bh * D_ * N_;
    const int q0 = qt * 64;
    const int sr = t >> 2, sk = (t & 3) * 8;

    // stage Q tile (64 x 64): two 8-elem halves per thread
    *reinterpret_cast<bf16x8*>(&Qs[sr][sk]) =
        *reinterpret_cast<const bf16x8*>(&kh[(size_t)(q0 + sr) * D_ + sk]);
    *reinterpret_cast<bf16x8*>(&Qs[sr][sk + 32]) =
        *reinterpret_cast<const bf16x8*>(&kh[(size_t)(q0 + sr) * D_ + sk + 32]);

    float m_run[4], l_run[4];
    f32x4 acc[4] = {};
#pragma unroll
    for (int i = 0; i < 4; i++) { m_run[i] = -1e30f; l_run[i] = 0.f; }

    for (int jt = 0; jt < 16; jt++) {
        const int j0 = jt * 64;
        __syncthreads();
        *reinterpret_cast<bf16x8*>(&Ks[sr][sk]) =
            *reinterpret_cast<const bf16x8*>(&kh[(size_t)(j0 + sr) * D_ + sk]);
        *reinterpret_cast<bf16x8*>(&Ks[sr][sk + 32]) =
            *reinterpret_cast<const bf16x8*>(&kh[(size_t)(j0 + sr) * D_ + sk + 32]);
        *reinterpret_cast<bf16x8*>(&Vs[sr][sk]) =
            *reinterpret_cast<const bf16x8*>(&vh[(size_t)sr * N_ + j0 + sk]);
        *reinterpret_cast<bf16x8*>(&Vs[sr][sk + 32]) =
            *reinterpret_cast<const bf16x8*>(&vh[(size_t)sr * N_ + j0 + sk + 32]);
        __syncthreads();

        // S = Q K^T  (16 rows x 64 cols per wave)
        f32x4 s[4] = {};
        bf16x8 aq0 = *reinterpret_cast<const bf16x8*>(&Qs[w * 16 + lr][lg * 8]);
        bf16x8 aq1 = *reinterpret_cast<const bf16x8*>(&Qs[w * 16 + lr][32 + lg * 8]);
#pragma unroll
        for (int fn = 0; fn < 4; fn++) {
            bf16x8 bk0 = *reinterpret_cast<const bf16x8*>(&Ks[fn * 16 + lr][lg * 8]);
            bf16x8 bk1 = *reinterpret_cast<const bf16x8*>(&Ks[fn * 16 + lr][32 + lg * 8]);
            s[fn] = __builtin_amdgcn_mfma_f32_16x16x32_bf16(aq0, bk0, s[fn], 0, 0, 0);
            s[fn] = __builtin_amdgcn_mfma_f32_16x16x32_bf16(aq1, bk1, s[fn], 0, 0, 0);
        }

        float sc[4][4], rowmax[4];
#pragma unroll
        for (int i = 0; i < 4; i++) rowmax[i] = -1e30f;
#pragma unroll
        for (int fn = 0; fn < 4; fn++) {
            int gj = j0 + fn * 16 + lr;
#pragma unroll
            for (int i = 0; i < 4; i++) {
                int gq = q0 + w * 16 + lg * 4 + i;
                float v = s[fn][i] * alpha + pb[(size_t)gq * N_ + gj];
                sc[fn][i] = v;
                rowmax[i] = fmaxf(rowmax[i], v);
            }
        }
#pragma unroll
        for (int msk = 1; msk < 16; msk <<= 1)
#pragma unroll
            for (int i = 0; i < 4; i++) rowmax[i] = fmaxf(rowmax[i], __shfl_xor(rowmax[i], msk));

        float mnew[4], scl[4], rs[4];
#pragma unroll
        for (int i = 0; i < 4; i++) {
            mnew[i] = fmaxf(m_run[i], rowmax[i]);
            scl[i] = __expf(m_run[i] - mnew[i]);
            rs[i] = 0.f;
        }
#pragma unroll
        for (int fn = 0; fn < 4; fn++)
#pragma unroll
            for (int i = 0; i < 4; i++) {
                float p = __expf(sc[fn][i] - mnew[i]);
                sc[fn][i] = p;
                rs[i] += p;
            }
#pragma unroll
        for (int msk = 1; msk < 16; msk <<= 1)
#pragma unroll
            for (int i = 0; i < 4; i++) rs[i] += __shfl_xor(rs[i], msk);
#pragma unroll
        for (int i = 0; i < 4; i++) {
            l_run[i] = l_run[i] * scl[i] + rs[i];
            m_run[i] = mnew[i];
        }
#pragma unroll
        for (int fd = 0; fd < 4; fd++)
#pragma unroll
            for (int i = 0; i < 4; i++) acc[fd][i] *= scl[i];

        // P -> LDS (wave-private tile; same-wave DS ops are HW-ordered,
        // compiler fence stops TBAA reordering of the typed reload)
#pragma unroll
        for (int fn = 0; fn < 4; fn++)
#pragma unroll
            for (int i = 0; i < 4; i++)
                Ps[w][lg * 4 + i][fn * 16 + lr] = f2bf(sc[fn][i]);

        asm volatile("" ::: "memory");

        bf16x8 pa0 = *reinterpret_cast<const bf16x8*>(&Ps[w][lr][lg * 8]);
        bf16x8 pa1 = *reinterpret_cast<const bf16x8*>(&Ps[w][lr][32 + lg * 8]);
#pragma unroll
        for (int fd = 0; fd < 4; fd++) {
            bf16x8 bv0 = *reinterpret_cast<const bf16x8*>(&Vs[fd * 16 + lr][lg * 8]);
            bf16x8 bv1 = *reinterpret_cast<const bf16x8*>(&Vs[fd * 16 + lr][32 + lg * 8]);
            acc[fd] = __builtin_amdgcn_mfma_f32_16x16x32_bf16(pa0, bv0, acc[fd], 0, 0, 0);
            acc[fd] = __builtin_amdgcn_mfma_f32_16x16x32_bf16(pa1, bv1, acc[fd], 0, 0, 0);
        }
    }

#pragma unroll
    for (int fd = 0; fd < 4; fd++) {
        int dcol = h * 64 + fd * 16 + lr;
#pragma unroll
        for (int i = 0; i < 4; i++) {
            int gq = q0 + w * 16 + lg * 4 + i;
            oh[((size_t)(b * N_ + gq)) * DIM_ + dcol] = f2bf(acc[fd][i] / l_run[i]);
        }
    }
}

// ---------------- final = oh @ W_out^T + b_out -> FLOAT32 d_out ----------------
__global__ __launch_bounds__(256) void out_gemm(const unsigned short* __restrict__ ohb,
                                                const unsigned short* __restrict__ wob,
                                                const float* __restrict__ b_out,
                                                float* __restrict__ out) {
    __shared__ __align__(16) unsigned short As[64][40];
    __shared__ __align__(16) unsigned short Bs[64][40];
    const int m0 = blockIdx.x * 64;
    const int n0 = blockIdx.y * 64;
    const int t = threadIdx.x;
    const int w = t >> 6, l = t & 63;
    const int wr = (w >> 1) * 32, wc = (w & 1) * 32;
    const int lr = l & 15, lg = l >> 4;
    const int sr = t >> 2, sk = (t & 3) * 8;

    f32x4 acc[2][2] = {};

    for (int k0 = 0; k0 < DIM_; k0 += 32) {
        __syncthreads();
        *reinterpret_cast<bf16x8*>(&As[sr][sk]) =
            *reinterpret_cast<const bf16x8*>(&ohb[(size_t)(m0 + sr) * DIM_ + k0 + sk]);
        *reinterpret_cast<bf16x8*>(&Bs[sr][sk]) =
            *reinterpret_cast<const bf16x8*>(&wob[(size_t)(n0 + sr) * DIM_ + k0 + sk]);
        __syncthreads();
        bf16x8 a0 = *reinterpret_cast<const bf16x8*>(&As[wr + lr][lg * 8]);
        bf16x8 a1 = *reinterpret_cast<const bf16x8*>(&As[wr + 16 + lr][lg * 8]);
        bf16x8 b0 = *reinterpret_cast<const bf16x8*>(&Bs[wc + lr][lg * 8]);
        bf16x8 b1 = *reinterpret_cast<const bf16x8*>(&Bs[wc + 16 + lr][lg * 8]);
        acc[0][0] = __builtin_amdgcn_mfma_f32_16x16x32_bf16(a0, b0, acc[0][0], 0, 0, 0);
        acc[0][1] = __builtin_amdgcn_mfma_f32_16x16x32_bf16(a0, b1, acc[0][1], 0, 0, 0);
        acc[1][0] = __builtin_amdgcn_mfma_f32_16x16x32_bf16(a1, b0, acc[1][0], 0, 0, 0);
        acc[1][1] = __builtin_amdgcn_mfma_f32_16x16x32_bf16(a1, b1, acc[1][1], 0, 0, 0);
    }

#pragma unroll
    for (int fm = 0; fm < 2; fm++)
#pragma unroll
        for (int fn = 0; fn < 2; fn++) {
            int gn = n0 + wc + fn * 16 + lr;
            float bias = b_out[gn];
#pragma unroll
            for (int i = 0; i < 4; i++) {
                int gm = m0 + wr + fm * 16 + lg * 4 + i;
                out[(size_t)gm * DIM_ + gn] = acc[fm][fn][i] + bias;
            }
        }
}

extern "C" void kernel_launch(void* const* d_in, const int* in_sizes, int n_in,
                              void* d_out, int out_size, void* d_ws, size_t ws_size,
                              hipStream_t stream) {
    const float* x     = (const float*)d_in[0];
    const float* pos   = (const float*)d_in[1];
    const float* W_kv  = (const float*)d_in[2];
    const float* W_out = (const float*)d_in[3];
    const float* b_out = (const float*)d_in[4];
    const float* w_pos = (const float*)d_in[5];
    // d_in[6] = b_pos: scalar added to every score -> softmax-invariant -> unused.

    char* ws = (char*)d_ws;
    unsigned short* xb   = (unsigned short*)(ws);               // 8 MB   x in bf16
    unsigned short* wkv  = (unsigned short*)(ws + 8388608);     // 1 MB   W_kv bf16
    unsigned short* wout = (unsigned short*)(ws + 9437184);     // 0.5 MB W_out bf16
    unsigned short* kb   = (unsigned short*)(ws + 9961472);     // 8 MB   k[b][h][n][d]
    unsigned short* vt   = (unsigned short*)(ws + 18350080);    // 8 MB   v^T[b][h][d][n]
    float*          pb   = (float*)(ws + 26738688);             // 4 MB   pos_bias fp32
    unsigned short* oh   = (unsigned short*)(ws + 30932992);    // 8 MB   attn out (b,n,h*d)
    float*          out  = (float*)d_out;                       // FLOAT32 output

    cast_f32_bf16<<<4096, 256, 0, stream>>>(x, xb, (B_ * N_ * DIM_) / 4);
    cast_f32_bf16<<<512, 256, 0, stream>>>(W_kv, wkv, (2 * DIM_ * DIM_) / 4);
    cast_f32_bf16<<<256, 256, 0, stream>>>(W_out, wout, (DIM_ * DIM_) / 4);
    pos_bias_kernel<<<4096, 256, 0, stream>>>(pos, w_pos, pb);
    kv_gemm<<<dim3(128, 16), 256, 0, stream>>>(xb, wkv, kb, vt);
    attn_kernel<<<dim3(64, 16), 256, 0, stream>>>(kb, vt, pb, w_pos, oh);
    out_gemm<<<dim3(128, 8), 256, 0, stream>>>(oh, wout, b_out, out);
}